// Round 6
// baseline (224.790 us; speedup 1.0000x reference)
//
#include <hip/hip_runtime.h>

#define NSEG 511
#define NROWS 8            // rows 8..15 only
#define ROW0 8
#define K0 21              // first needed freq bin
#define KEND 500           // bins k with 20 < k < 500
#define NFREQ 479
#define ACC_STRIDE 512     // padded per-row accumulator stride
#define ACC_ELEMS (2 * NROWS * ACC_STRIDE)   // one replica
#define NREP 8             // accumulator replicas (cuts atomic contention 8x)
#define NBLOCKS (2 * NROWS * NSEG)

// XOR swizzle: permutes the i-digit (bits 2..4) by the j-digit (bits 5..7).
// Keeps bits 0..1 intact (quads stay contiguous), bijective per 32-block.
__device__ __forceinline__ int sw(int i) { return i ^ (((i >> 5) & 7) << 2); }

__device__ __forceinline__ float2 cmul(float2 a, float2 b) {
    return make_float2(fmaf(a.x, b.x, -a.y * b.y), fmaf(a.x, b.y, a.y * b.x));
}
__device__ __forceinline__ float2 cadd(float2 a, float2 b) { return make_float2(a.x + b.x, a.y + b.y); }
__device__ __forceinline__ float2 csub(float2 a, float2 b) { return make_float2(a.x - b.x, a.y - b.y); }

// In-register 8-point DFT (DIF).
__device__ __forceinline__ void dft8(float2& x0, float2& x1, float2& x2, float2& x3,
                                     float2& x4, float2& x5, float2& x6, float2& x7) {
    const float C45 = 0.70710678118654752440f;
    float2 t0 = cadd(x0, x4), u0 = csub(x0, x4);
    float2 t1 = cadd(x1, x5), u1 = csub(x1, x5);
    float2 t2 = cadd(x2, x6), u2 = csub(x2, x6);
    float2 t3 = cadd(x3, x7), u3 = csub(x3, x7);
    float2 s0 = cadd(t0, t2), d0 = csub(t0, t2);
    float2 s1 = cadd(t1, t3), d1 = csub(t1, t3);
    float2 v1 = make_float2(C45 * (u1.x + u1.y), C45 * (u1.y - u1.x));
    float2 v2 = make_float2(u2.y, -u2.x);
    float2 v3 = make_float2(C45 * (u3.y - u3.x), -C45 * (u3.x + u3.y));
    float2 s2 = cadd(u0, v2), d2 = csub(u0, v2);
    float2 s3 = cadd(v1, v3), d3 = csub(v1, v3);
    float2 mid1 = make_float2(d1.y, -d1.x);   // -i * d1
    float2 mid3 = make_float2(d3.y, -d3.x);   // -i * d3
    x0 = cadd(s0, s1); x4 = csub(s0, s1);
    x2 = cadd(d0, mid1); x6 = csub(d0, mid1);
    x1 = cadd(s2, s3); x5 = csub(s2, s3);
    x3 = cadd(d2, mid3); x7 = csub(d2, mid3);
}

// x[p] *= W^p with W = (c, s) given; 6 cmuls to build powers, 7 to apply.
__device__ __forceinline__ void twiddle8cs(float2& x1, float2& x2, float2& x3, float2& x4,
                                           float2& x5, float2& x6, float2& x7,
                                           float c, float s) {
    float2 w1 = make_float2(c, s);
    float2 w2 = cmul(w1, w1);
    float2 w3 = cmul(w2, w1);
    float2 w4 = cmul(w2, w2);
    float2 w5 = cmul(w4, w1);
    float2 w6 = cmul(w3, w3);
    float2 w7 = cmul(w4, w3);
    x1 = cmul(x1, w1); x2 = cmul(x2, w2); x3 = cmul(x3, w3);
    x4 = cmul(x4, w4); x5 = cmul(x5, w5); x6 = cmul(x6, w6);
    x7 = cmul(x7, w7);
}

// One block = one (signal, row, segment). Windowed 4096-pt real FFT via
// register-resident 2048-pt complex FFT, radices [8,8,8,(4 fused into the
// untangle)], 2 barriers total. Fire-and-forget atomics into replica bid&7.
__global__ __launch_bounds__(256)
void psd_kernel(const float* __restrict__ pred,
                const float* __restrict__ target,
                float* __restrict__ acc) {
    __shared__ float2 buf[2048];   // 16 KiB

    const int bid = blockIdx.x;
    const int seg = bid % NSEG;
    const int row = (bid / NSEG) % NROWS + ROW0;
    const int sig = bid / (NSEG * NROWS);   // 0 = res (target-pred), 1 = target
    const int tid = threadIdx.x;
    float* accR = acc + (bid & (NREP - 1)) * ACC_ELEMS;

    const float2* t2p = (const float2*)target;
    const float2* p2p = (const float2*)pred;

    // ---- load + window into named registers.
    // Complex point m = (real[2m], real[2m+1]); m = tid + 256*r.
    // Real sample 2m is at batch row 2*seg + (m>>9), float2 offset row*512 + (m&511).
    // w[2m] = 1 - cos(m*WA); w[2m+1] = 1 - cos(m*WA + pi/2048).
    // Angle m*WA = tid*WA + r*pi/4 -> ONE sincos + exact pi/4 rotations.
    const float WA = 3.06796157577128245e-3f;      // 2*pi/2048
    const float CD = 0.99999882344642529f;         // cos(pi/2048)
    const float SD = 1.53398018628476550e-3f;      // sin(pi/2048)
    const float H  = 0.70710678118654752440f;      // sqrt(2)/2
    float sa, ca;
    __sincosf((float)tid * WA, &sa, &ca);

    const int base2 = 2 * seg * 8192 + row * 512 + tid;
    float2 x0, x1, x2, x3, x4, x5, x6, x7;
#define LOADW(R, X, CE, SE)                                                  \
    {                                                                        \
        int idx2 = base2 + ((R) >> 1) * 8192 + ((R) & 1) * 256;              \
        float2 v = t2p[idx2];                                                \
        if (sig == 0) { float2 p = p2p[idx2]; v.x -= p.x; v.y -= p.y; }      \
        float cr = (CE), sr = (SE);                                          \
        X = make_float2(v.x * (1.0f - cr),                                   \
                        v.y * (1.0f - (cr * CD - sr * SD)));                 \
    }
    LOADW(0, x0, ca, sa)
    LOADW(1, x1, H * (ca - sa), H * (sa + ca))
    LOADW(2, x2, -sa, ca)
    LOADW(3, x3, -H * (ca + sa), H * (ca - sa))
    LOADW(4, x4, -ca, -sa)
    LOADW(5, x5, H * (sa - ca), -H * (sa + ca))
    LOADW(6, x6, sa, -ca)
    LOADW(7, x7, H * (ca + sa), H * (sa - ca))
#undef LOADW

    // ---- stage A: radix-8 over stride 256 (q = tid), twiddle W2048^{q*p}.
    // W2048^q = e^{-i*tid*WA} = (ca, -sa): reuse the window sincos (free).
    dft8(x0, x1, x2, x3, x4, x5, x6, x7);
    twiddle8cs(x1, x2, x3, x4, x5, x6, x7, ca, -sa);
    buf[sw(tid)]        = x0;
    buf[sw(tid + 256)]  = x1;
    buf[sw(tid + 512)]  = x2;
    buf[sw(tid + 768)]  = x3;
    buf[sw(tid + 1024)] = x4;
    buf[sw(tid + 1280)] = x5;
    buf[sw(tid + 1536)] = x6;
    buf[sw(tid + 1792)] = x7;
    __syncthreads();

    // ---- stage B: radix-8 over stride 32 within each 256-subFFT.
    {
        const int pb = tid >> 5, q0 = tid & 31;
        const int baseB = q0 + 256 * pb;
        x0 = buf[sw(baseB)];
        x1 = buf[sw(baseB + 32)];
        x2 = buf[sw(baseB + 64)];
        x3 = buf[sw(baseB + 96)];
        x4 = buf[sw(baseB + 128)];
        x5 = buf[sw(baseB + 160)];
        x6 = buf[sw(baseB + 192)];
        x7 = buf[sw(baseB + 224)];
        dft8(x0, x1, x2, x3, x4, x5, x6, x7);
        float sb, cb;
        __sincosf((float)q0 * -2.45436926061702596e-2f, &sb, &cb);  // -2*pi/256
        twiddle8cs(x1, x2, x3, x4, x5, x6, x7, cb, sb);
        buf[sw(baseB)]       = x0;
        buf[sw(baseB + 32)]  = x1;
        buf[sw(baseB + 64)]  = x2;
        buf[sw(baseB + 96)]  = x3;
        buf[sw(baseB + 128)] = x4;
        buf[sw(baseB + 160)] = x5;
        buf[sw(baseB + 192)] = x6;
        buf[sw(baseB + 224)] = x7;
    }
    // B->C exchange stays inside a 32-thread group (same wave): no block
    // barrier needed, just drain LDS writes + stop compiler reordering.
    asm volatile("s_waitcnt lgkmcnt(0)" ::: "memory");

    // ---- stage C: radix-8 over stride 4 within each 32-subFFT.
    {
        const int pb2 = tid >> 5, j2 = (tid >> 2) & 7, mq = tid & 3;
        const int baseC = mq + 32 * j2 + 256 * pb2;
        x0 = buf[sw(baseC)];
        x1 = buf[sw(baseC + 4)];
        x2 = buf[sw(baseC + 8)];
        x3 = buf[sw(baseC + 12)];
        x4 = buf[sw(baseC + 16)];
        x5 = buf[sw(baseC + 20)];
        x6 = buf[sw(baseC + 24)];
        x7 = buf[sw(baseC + 28)];
        dft8(x0, x1, x2, x3, x4, x5, x6, x7);
        // twiddle W32^{mq*i}, mq in {0..3}: constants, no sincos
        const float TC1 = 0.98078528040323044913f, TS1 = -0.19509032201612826785f;
        const float TC2 = 0.92387953251128675613f, TS2 = -0.38268343236508977173f;
        const float TC3 = 0.83146961230254523708f, TS3 = -0.55557023301960222474f;
        float cc = (mq & 2) ? ((mq & 1) ? TC3 : TC2) : ((mq & 1) ? TC1 : 1.0f);
        float ss = (mq & 2) ? ((mq & 1) ? TS3 : TS2) : ((mq & 1) ? TS1 : 0.0f);
        twiddle8cs(x1, x2, x3, x4, x5, x6, x7, cc, ss);
        buf[sw(baseC)]      = x0;
        buf[sw(baseC + 4)]  = x1;
        buf[sw(baseC + 8)]  = x2;
        buf[sw(baseC + 12)] = x3;
        buf[sw(baseC + 16)] = x4;
        buf[sw(baseC + 20)] = x5;
        buf[sw(baseC + 24)] = x6;
        buf[sw(baseC + 28)] = x7;
    }
    __syncthreads();

    // ---- fused final radix-4 + untangle + power + accumulate.
    // Pre-stage-D layout: position mq + 4i + 32j + 256p holds input mq of the
    // length-4 DFT for bin k = 512v + 64i + 8j + p (output v).
    // Bin k in [21,500)  -> v=0: Z[k]      = a0+a1+a2+a3
    // Bin 2048-k         -> v=3: Z[2048-k] = (a0-a2) + i(a1-a3)
    // Lane permutation k = K0 + ((n&7)<<6 | n>>3) de-conflicts the quad reads.
    const int kk0 = K0 + (((tid & 7) << 6) | (tid >> 3));
    float sn0, cs0;
    __sincosf(-1.53398078788564123e-3f * (float)kk0, &sn0, &cs0);  // -2*pi*k/4096
#define UNTANGLE(KK, CS, SN)                                                 \
    {                                                                        \
        int kk = (KK);                                                       \
        if (kk < KEND) {                                                     \
            int bk = 4 * ((kk >> 6) & 7) + 32 * ((kk >> 3) & 7) + 256 * (kk & 7); \
            int sbk = sw(bk);                                                \
            float2 a0 = buf[sbk], a1 = buf[sbk + 1];                         \
            float2 a2 = buf[sbk + 2], a3 = buf[sbk + 3];                     \
            float2 zk = make_float2((a0.x + a2.x) + (a1.x + a3.x),           \
                                    (a0.y + a2.y) + (a1.y + a3.y));          \
            int m = 2048 - kk;                                               \
            int bm = 4 * ((m >> 6) & 7) + 32 * ((m >> 3) & 7) + 256 * (m & 7); \
            int sbm = sw(bm);                                                \
            float2 b0 = buf[sbm], b1 = buf[sbm + 1];                         \
            float2 b2 = buf[sbm + 2], b3 = buf[sbm + 3];                     \
            float2 zn = make_float2((b0.x - b2.x) - (b1.y - b3.y),           \
                                    (b0.y - b2.y) + (b1.x - b3.x));          \
            float Ex = 0.5f * (zk.x + zn.x);                                 \
            float Ey = 0.5f * (zk.y - zn.y);                                 \
            float Ox = 0.5f * (zk.y + zn.y);                                 \
            float Oy = -0.5f * (zk.x - zn.x);                                \
            float xr = Ex + Ox * (CS) - Oy * (SN);                           \
            float xi = Ey + Ox * (SN) + Oy * (CS);                           \
            float pw = xr * xr + xi * xi;                                    \
            atomicAdd(&accR[(sig * NROWS + (row - ROW0)) * ACC_STRIDE + (kk - K0)], pw); \
        }                                                                    \
    }
    UNTANGLE(kk0, cs0, sn0)
    // second bin: k + 32 -> rotate twiddle by -pi/64 (constants)
    {
        const float CU = 0.99879545620517240501f;   // cos(pi/64)
        const float SU = 0.04906767432741801426f;   // sin(pi/64)
        float cs1 = cs0 * CU + sn0 * SU;
        float sn1 = sn0 * CU - cs0 * SU;
        UNTANGLE(kk0 + 32, cs1, sn1)
    }
#undef UNTANGLE
}

// Single block: out = sum over (row,k) of P_res/P_tgt, / 240.
// (dfreq=1, scale=480, mean(last 8)*16 => 2/480 = 1/240; /T cancels in ratio)
__global__ __launch_bounds__(256)
void reduce_kernel(const float* __restrict__ acc, float* __restrict__ out) {
    __shared__ float sh[256];
    int tid = threadIdx.x;
    float sum = 0.0f;
    for (int n = tid; n < NROWS * NFREQ; n += 256) {
        int r = n / NFREQ, k = n % NFREQ;
        float num = 0.0f, den = 0.0f;
        #pragma unroll
        for (int rep = 0; rep < NREP; ++rep) {
            num += acc[rep * ACC_ELEMS + r * ACC_STRIDE + k];
            den += acc[rep * ACC_ELEMS + (NROWS + r) * ACC_STRIDE + k];
        }
        sum += num / den;
    }
    sh[tid] = sum;
    __syncthreads();
    for (int s = 128; s > 0; s >>= 1) {
        if (tid < s) sh[tid] += sh[tid + s];
        __syncthreads();
    }
    if (tid == 0) out[0] = sh[0] * (1.0f / 240.0f);
}

extern "C" void kernel_launch(void* const* d_in, const int* in_sizes, int n_in,
                              void* d_out, int out_size, void* d_ws, size_t ws_size,
                              hipStream_t stream) {
    const float* pred = (const float*)d_in[0];
    const float* target = (const float*)d_in[1];
    float* acc = (float*)d_ws;   // NREP replicas of [2][NROWS][ACC_STRIDE] = 256 KiB

    hipMemsetAsync(acc, 0, NREP * ACC_ELEMS * sizeof(float), stream);
    psd_kernel<<<NBLOCKS, 256, 0, stream>>>(pred, target, acc);
    reduce_kernel<<<1, 256, 0, stream>>>(acc, (float*)d_out);
}

// Round 7
// 188.624 us; speedup vs baseline: 1.1917x; 1.1917x over previous
//
#include <hip/hip_runtime.h>

#define NSEG 511
#define NROWS 8            // rows 8..15 only
#define ROW0 8
#define K0 21              // first needed freq bin
#define KEND 500           // bins k with 20 < k < 500
#define NFREQ 479
#define ACC_STRIDE 512     // padded per-row accumulator stride
#define ACC_ELEMS (2 * NROWS * ACC_STRIDE)   // one replica
#define NREP 8             // accumulator replicas (cuts atomic contention 8x)
#define NBLOCKS (2 * NROWS * NSEG)

// XOR swizzle: permutes the i-digit (bits 2..4) by the j-digit (bits 5..7).
// Keeps bits 0..1 intact (float4 groups stay contiguous), bijective per 32-block.
__device__ __forceinline__ int sw(int i) { return i ^ (((i >> 5) & 7) << 2); }

// Position of bin k after in-place DIF with radices [8,8,8,4]:
// k = 512*k3 + 64*i + 8*j + p  ->  pos = k3 + 4*i + 32*j + 256*p
__device__ __forceinline__ int dr_pos(int k) {
    return ((k >> 9) & 3) + 4 * ((k >> 6) & 7) + 32 * ((k >> 3) & 7) + 256 * (k & 7);
}

__device__ __forceinline__ float2 cmul(float2 a, float2 b) {
    return make_float2(fmaf(a.x, b.x, -a.y * b.y), fmaf(a.x, b.y, a.y * b.x));
}
__device__ __forceinline__ float2 cadd(float2 a, float2 b) { return make_float2(a.x + b.x, a.y + b.y); }
__device__ __forceinline__ float2 csub(float2 a, float2 b) { return make_float2(a.x - b.x, a.y - b.y); }

// In-register 8-point DFT (DIF).
__device__ __forceinline__ void dft8(float2& x0, float2& x1, float2& x2, float2& x3,
                                     float2& x4, float2& x5, float2& x6, float2& x7) {
    const float C45 = 0.70710678118654752440f;
    float2 t0 = cadd(x0, x4), u0 = csub(x0, x4);
    float2 t1 = cadd(x1, x5), u1 = csub(x1, x5);
    float2 t2 = cadd(x2, x6), u2 = csub(x2, x6);
    float2 t3 = cadd(x3, x7), u3 = csub(x3, x7);
    float2 s0 = cadd(t0, t2), d0 = csub(t0, t2);
    float2 s1 = cadd(t1, t3), d1 = csub(t1, t3);
    float2 v1 = make_float2(C45 * (u1.x + u1.y), C45 * (u1.y - u1.x));
    float2 v2 = make_float2(u2.y, -u2.x);
    float2 v3 = make_float2(C45 * (u3.y - u3.x), -C45 * (u3.x + u3.y));
    float2 s2 = cadd(u0, v2), d2 = csub(u0, v2);
    float2 s3 = cadd(v1, v3), d3 = csub(v1, v3);
    float2 mid1 = make_float2(d1.y, -d1.x);   // -i * d1
    float2 mid3 = make_float2(d3.y, -d3.x);   // -i * d3
    x0 = cadd(s0, s1); x4 = csub(s0, s1);
    x2 = cadd(d0, mid1); x6 = csub(d0, mid1);
    x1 = cadd(s2, s3); x5 = csub(s2, s3);
    x3 = cadd(d2, mid3); x7 = csub(d2, mid3);
}

// x[p] *= W^p with W = (c, s) given; 6 cmuls to build powers, 7 to apply.
__device__ __forceinline__ void twiddle8cs(float2& x1, float2& x2, float2& x3, float2& x4,
                                           float2& x5, float2& x6, float2& x7,
                                           float c, float s) {
    float2 w1 = make_float2(c, s);
    float2 w2 = cmul(w1, w1);
    float2 w3 = cmul(w2, w1);
    float2 w4 = cmul(w2, w2);
    float2 w5 = cmul(w4, w1);
    float2 w6 = cmul(w3, w3);
    float2 w7 = cmul(w4, w3);
    x1 = cmul(x1, w1); x2 = cmul(x2, w2); x3 = cmul(x3, w3);
    x4 = cmul(x4, w4); x5 = cmul(x5, w5); x6 = cmul(x6, w6);
    x7 = cmul(x7, w7);
}

// One block = one (signal, row, segment). Windowed 4096-pt real FFT via
// register-resident 2048-pt complex FFT, radices [8,8,8,4], R5 structure
// (3 LDS exchanges + float4 stage D, all __syncthreads kept).
// Only 3 sincos/thread: window+stageA share one, stage B one, untangle one.
__global__ __launch_bounds__(256)
void psd_kernel(const float* __restrict__ pred,
                const float* __restrict__ target,
                float* __restrict__ acc) {
    __shared__ float2 buf[2048];   // 16 KiB

    const int bid = blockIdx.x;
    const int seg = bid % NSEG;
    const int row = (bid / NSEG) % NROWS + ROW0;
    const int sig = bid / (NSEG * NROWS);   // 0 = res (target-pred), 1 = target
    const int tid = threadIdx.x;
    float* accR = acc + (bid & (NREP - 1)) * ACC_ELEMS;

    const float2* t2p = (const float2*)target;
    const float2* p2p = (const float2*)pred;

    // ---- load + window into named registers.
    // Complex point m = (real[2m], real[2m+1]); m = tid + 256*r.
    // Real sample 2m is at batch row 2*seg + (m>>9), float2 offset row*512 + (m&511).
    // w[2m] = 1 - cos(m*WA); w[2m+1] = 1 - cos(m*WA + pi/2048).
    // Angle m*WA = tid*WA + r*pi/4 -> ONE sincos + exact pi/4 rotations.
    const float WA = 3.06796157577128245e-3f;      // 2*pi/2048
    const float CD = 0.99999882344642529f;         // cos(pi/2048)
    const float SD = 1.53398018628476550e-3f;      // sin(pi/2048)
    const float H  = 0.70710678118654752440f;      // sqrt(2)/2
    float sa, ca;
    __sincosf((float)tid * WA, &sa, &ca);

    const int base2 = 2 * seg * 8192 + row * 512 + tid;
    float2 x0, x1, x2, x3, x4, x5, x6, x7;
#define LOADW(R, X, CE, SE)                                                  \
    {                                                                        \
        int idx2 = base2 + ((R) >> 1) * 8192 + ((R) & 1) * 256;              \
        float2 v = t2p[idx2];                                                \
        if (sig == 0) { float2 p = p2p[idx2]; v.x -= p.x; v.y -= p.y; }      \
        float cr = (CE), sr = (SE);                                          \
        X = make_float2(v.x * (1.0f - cr),                                   \
                        v.y * (1.0f - (cr * CD - sr * SD)));                 \
    }
    LOADW(0, x0, ca, sa)
    LOADW(1, x1, H * (ca - sa), H * (sa + ca))
    LOADW(2, x2, -sa, ca)
    LOADW(3, x3, -H * (ca + sa), H * (ca - sa))
    LOADW(4, x4, -ca, -sa)
    LOADW(5, x5, H * (sa - ca), -H * (sa + ca))
    LOADW(6, x6, sa, -ca)
    LOADW(7, x7, H * (ca + sa), H * (sa - ca))
#undef LOADW

    // ---- stage A: radix-8 over stride 256 (q = tid), twiddle W2048^{q*p}.
    // W2048^tid = e^{-i*tid*WA} = (ca, -sa): conjugate of the window base, free.
    dft8(x0, x1, x2, x3, x4, x5, x6, x7);
    twiddle8cs(x1, x2, x3, x4, x5, x6, x7, ca, -sa);
    buf[sw(tid)]        = x0;
    buf[sw(tid + 256)]  = x1;
    buf[sw(tid + 512)]  = x2;
    buf[sw(tid + 768)]  = x3;
    buf[sw(tid + 1024)] = x4;
    buf[sw(tid + 1280)] = x5;
    buf[sw(tid + 1536)] = x6;
    buf[sw(tid + 1792)] = x7;
    __syncthreads();

    // ---- stage B: radix-8 over stride 32 within each 256-subFFT.
    {
        const int pb = tid >> 5, q0 = tid & 31;
        const int baseB = q0 + 256 * pb;
        x0 = buf[sw(baseB)];
        x1 = buf[sw(baseB + 32)];
        x2 = buf[sw(baseB + 64)];
        x3 = buf[sw(baseB + 96)];
        x4 = buf[sw(baseB + 128)];
        x5 = buf[sw(baseB + 160)];
        x6 = buf[sw(baseB + 192)];
        x7 = buf[sw(baseB + 224)];
        dft8(x0, x1, x2, x3, x4, x5, x6, x7);
        float sb, cb;
        __sincosf((float)q0 * -2.45436926061702596e-2f, &sb, &cb);  // -2*pi/256
        twiddle8cs(x1, x2, x3, x4, x5, x6, x7, cb, sb);
        buf[sw(baseB)]       = x0;
        buf[sw(baseB + 32)]  = x1;
        buf[sw(baseB + 64)]  = x2;
        buf[sw(baseB + 96)]  = x3;
        buf[sw(baseB + 128)] = x4;
        buf[sw(baseB + 160)] = x5;
        buf[sw(baseB + 192)] = x6;
        buf[sw(baseB + 224)] = x7;
    }
    __syncthreads();

    // ---- stage C: radix-8 over stride 4 within each 32-subFFT.
    {
        const int pb2 = tid >> 5, j2 = (tid >> 2) & 7, mq = tid & 3;
        const int baseC = mq + 32 * j2 + 256 * pb2;
        x0 = buf[sw(baseC)];
        x1 = buf[sw(baseC + 4)];
        x2 = buf[sw(baseC + 8)];
        x3 = buf[sw(baseC + 12)];
        x4 = buf[sw(baseC + 16)];
        x5 = buf[sw(baseC + 20)];
        x6 = buf[sw(baseC + 24)];
        x7 = buf[sw(baseC + 28)];
        dft8(x0, x1, x2, x3, x4, x5, x6, x7);
        // twiddle W32^{mq*i}, mq in {0..3}: constants, no sincos
        const float TC1 = 0.98078528040323044913f, TS1 = -0.19509032201612826785f;
        const float TC2 = 0.92387953251128675613f, TS2 = -0.38268343236508977173f;
        const float TC3 = 0.83146961230254523708f, TS3 = -0.55557023301960222474f;
        float cc = (mq & 2) ? ((mq & 1) ? TC3 : TC2) : ((mq & 1) ? TC1 : 1.0f);
        float ss = (mq & 2) ? ((mq & 1) ? TS3 : TS2) : ((mq & 1) ? TS1 : 0.0f);
        twiddle8cs(x1, x2, x3, x4, x5, x6, x7, cc, ss);
        buf[sw(baseC)]      = x0;
        buf[sw(baseC + 4)]  = x1;
        buf[sw(baseC + 8)]  = x2;
        buf[sw(baseC + 12)] = x3;
        buf[sw(baseC + 16)] = x4;
        buf[sw(baseC + 20)] = x5;
        buf[sw(baseC + 24)] = x6;
        buf[sw(baseC + 28)] = x7;
    }
    __syncthreads();

    // ---- stage D: 512 length-4 DFTs over contiguous quads (twiddle-free),
    // each thread does 2, via float4 pairs (swizzle keeps quads contiguous).
    float4* b4 = (float4*)buf;
#define STAGE_D(G)                                                           \
    {                                                                        \
        int pbase = sw(4 * (tid + 256 * (G)));                               \
        float4 lo = b4[(pbase >> 1)];                                        \
        float4 hi = b4[(pbase >> 1) + 1];                                    \
        float2 a0 = make_float2(lo.x, lo.y), a1 = make_float2(lo.z, lo.w);   \
        float2 a2 = make_float2(hi.x, hi.y), a3 = make_float2(hi.z, hi.w);   \
        float2 S0 = cadd(a0, a2), D0 = csub(a0, a2);                         \
        float2 S1 = cadd(a1, a3), D1 = csub(a1, a3);                         \
        float2 mi = make_float2(D1.y, -D1.x);                                \
        float2 X0 = cadd(S0, S1), X2 = csub(S0, S1);                         \
        float2 X1 = cadd(D0, mi), X3 = csub(D0, mi);                         \
        b4[(pbase >> 1)]     = make_float4(X0.x, X0.y, X1.x, X1.y);          \
        b4[(pbase >> 1) + 1] = make_float4(X2.x, X2.y, X3.x, X3.y);          \
    }
    STAGE_D(0) STAGE_D(1)
#undef STAGE_D
    __syncthreads();

    // ---- untangle real FFT + power + accumulate (bins 21..499).
    // One sincos for bin k = K0+tid; bin k+256 via exact -pi/8 rotation.
    {
        int k = K0 + tid;
        float sn0, cs0;
        __sincosf(-1.53398078788564123e-3f * (float)k, &sn0, &cs0);  // -2*pi*k/4096
#define UNTANGLE(KK, CS, SN)                                                 \
        {                                                                    \
            int kk = (KK);                                                   \
            if (kk < KEND) {                                                 \
                float2 zk = buf[sw(dr_pos(kk))];                             \
                float2 zn = buf[sw(dr_pos(2048 - kk))];                      \
                float Ex = 0.5f * (zk.x + zn.x);                             \
                float Ey = 0.5f * (zk.y - zn.y);                             \
                float Ox = 0.5f * (zk.y + zn.y);                             \
                float Oy = -0.5f * (zk.x - zn.x);                            \
                float xr = Ex + Ox * (CS) - Oy * (SN);                       \
                float xi = Ey + Ox * (SN) + Oy * (CS);                       \
                float pw = xr * xr + xi * xi;                                \
                atomicAdd(&accR[(sig * NROWS + (row - ROW0)) * ACC_STRIDE + (kk - K0)], pw); \
            }                                                                \
        }
        UNTANGLE(k, cs0, sn0)
        {
            const float CU = 0.98078528040323044913f;   // cos(pi/8)
            const float SU = 0.19509032201612826785f;   // sin(pi/8)
            float cs1 = cs0 * CU + sn0 * SU;            // ang - pi/8
            float sn1 = sn0 * CU - cs0 * SU;
            UNTANGLE(k + 256, cs1, sn1)
        }
#undef UNTANGLE
    }
}

// Single block: out = sum over (row,k) of P_res/P_tgt, / 240.
// (dfreq=1, scale=480, mean(last 8)*16 => 2/480 = 1/240; /T cancels in ratio)
__global__ __launch_bounds__(256)
void reduce_kernel(const float* __restrict__ acc, float* __restrict__ out) {
    __shared__ float sh[256];
    int tid = threadIdx.x;
    float sum = 0.0f;
    for (int n = tid; n < NROWS * NFREQ; n += 256) {
        int r = n / NFREQ, k = n % NFREQ;
        float num = 0.0f, den = 0.0f;
        #pragma unroll
        for (int rep = 0; rep < NREP; ++rep) {
            num += acc[rep * ACC_ELEMS + r * ACC_STRIDE + k];
            den += acc[rep * ACC_ELEMS + (NROWS + r) * ACC_STRIDE + k];
        }
        sum += num / den;
    }
    sh[tid] = sum;
    __syncthreads();
    for (int s = 128; s > 0; s >>= 1) {
        if (tid < s) sh[tid] += sh[tid + s];
        __syncthreads();
    }
    if (tid == 0) out[0] = sh[0] * (1.0f / 240.0f);
}

extern "C" void kernel_launch(void* const* d_in, const int* in_sizes, int n_in,
                              void* d_out, int out_size, void* d_ws, size_t ws_size,
                              hipStream_t stream) {
    const float* pred = (const float*)d_in[0];
    const float* target = (const float*)d_in[1];
    float* acc = (float*)d_ws;   // NREP replicas of [2][NROWS][ACC_STRIDE] = 256 KiB

    hipMemsetAsync(acc, 0, NREP * ACC_ELEMS * sizeof(float), stream);
    psd_kernel<<<NBLOCKS, 256, 0, stream>>>(pred, target, acc);
    reduce_kernel<<<1, 256, 0, stream>>>(acc, (float*)d_out);
}

// Round 8
// 168.785 us; speedup vs baseline: 1.3318x; 1.1175x over previous
//
#include <hip/hip_runtime.h>

#define NSEG 511
#define NROWS 8            // rows 8..15 only
#define ROW0 8
#define K0 21              // first needed freq bin
#define KEND 500           // bins k with 20 < k < 500
#define NFREQ 479
#define ACC_STRIDE 512     // padded per-row accumulator stride
#define ACC_ELEMS (2 * NROWS * ACC_STRIDE)   // one replica
#define NREP 8             // accumulator replicas
#define SPB 4              // segments per block
#define NGROUPS 128        // ceil(511/4)
#define NBLOCKS (2 * NROWS * NGROUPS)

// XOR swizzle for the FFT buffer (keeps quads contiguous).
__device__ __forceinline__ int sw(int i) { return i ^ (((i >> 5) & 7) << 2); }
// XOR swizzle for the natural-order buffer: de-conflicts the stage-D scatter
// writes (i-digit into bits 0..2) while keeping linear reads conflict-free.
__device__ __forceinline__ int ms(int m) { return m ^ ((m >> 6) & 7); }

__device__ __forceinline__ float2 cmul(float2 a, float2 b) {
    return make_float2(fmaf(a.x, b.x, -a.y * b.y), fmaf(a.x, b.y, a.y * b.x));
}
__device__ __forceinline__ float2 cadd(float2 a, float2 b) { return make_float2(a.x + b.x, a.y + b.y); }
__device__ __forceinline__ float2 csub(float2 a, float2 b) { return make_float2(a.x - b.x, a.y - b.y); }

// In-register 8-point DFT (DIF).
__device__ __forceinline__ void dft8(float2& x0, float2& x1, float2& x2, float2& x3,
                                     float2& x4, float2& x5, float2& x6, float2& x7) {
    const float C45 = 0.70710678118654752440f;
    float2 t0 = cadd(x0, x4), u0 = csub(x0, x4);
    float2 t1 = cadd(x1, x5), u1 = csub(x1, x5);
    float2 t2 = cadd(x2, x6), u2 = csub(x2, x6);
    float2 t3 = cadd(x3, x7), u3 = csub(x3, x7);
    float2 s0 = cadd(t0, t2), d0 = csub(t0, t2);
    float2 s1 = cadd(t1, t3), d1 = csub(t1, t3);
    float2 v1 = make_float2(C45 * (u1.x + u1.y), C45 * (u1.y - u1.x));
    float2 v2 = make_float2(u2.y, -u2.x);
    float2 v3 = make_float2(C45 * (u3.y - u3.x), -C45 * (u3.x + u3.y));
    float2 s2 = cadd(u0, v2), d2 = csub(u0, v2);
    float2 s3 = cadd(v1, v3), d3 = csub(v1, v3);
    float2 mid1 = make_float2(d1.y, -d1.x);   // -i * d1
    float2 mid3 = make_float2(d3.y, -d3.x);   // -i * d3
    x0 = cadd(s0, s1); x4 = csub(s0, s1);
    x2 = cadd(d0, mid1); x6 = csub(d0, mid1);
    x1 = cadd(s2, s3); x5 = csub(s2, s3);
    x3 = cadd(d2, mid3); x7 = csub(d2, mid3);
}

// x[p] *= W^p with W = (c, s) given.
__device__ __forceinline__ void twiddle8cs(float2& x1, float2& x2, float2& x3, float2& x4,
                                           float2& x5, float2& x6, float2& x7,
                                           float c, float s) {
    float2 w1 = make_float2(c, s);
    float2 w2 = cmul(w1, w1);
    float2 w3 = cmul(w2, w1);
    float2 w4 = cmul(w2, w2);
    float2 w5 = cmul(w4, w1);
    float2 w6 = cmul(w3, w3);
    float2 w7 = cmul(w4, w3);
    x1 = cmul(x1, w1); x2 = cmul(x2, w2); x3 = cmul(x3, w3);
    x4 = cmul(x4, w4); x5 = cmul(x5, w5); x6 = cmul(x6, w6);
    x7 = cmul(x7, w7);
}

// One block = one (signal, row, 4 consecutive segments). Per segment: windowed
// 4096-pt real FFT via register 2048-pt complex FFT (radices [8,8,8,4-fused]).
// Power accumulated in registers across segments; ONE atomic flush per thread.
__global__ __launch_bounds__(256)
void psd_kernel(const float* __restrict__ pred,
                const float* __restrict__ target,
                float* __restrict__ acc) {
    __shared__ float2 buf[2048];   // 16 KiB FFT workspace
    __shared__ float2 nat[1024];   // 8 KiB: natA=[0,512) X0 bins, natB=[512,1024) X3 bins

    const int bid = blockIdx.x;
    const int grp = bid % NGROUPS;
    const int row = (bid / NGROUPS) % NROWS + ROW0;
    const int sig = bid / (NGROUPS * NROWS);   // 0 = res (target-pred), 1 = target
    const int tid = threadIdx.x;
    const int seg0 = grp * SPB;
    const int ns = (seg0 + SPB <= NSEG) ? SPB : (NSEG - seg0);   // 4 (last group: 3)
    float* accR = acc + (bid & (NREP - 1)) * ACC_ELEMS;

    const float2* t2p = (const float2*)target;
    const float2* p2p = (const float2*)pred;

    // Complex point m of segment s: real samples at batch row 2(seg0+s)+(m>>9),
    // float2 offset row*512 + (m&511). m = tid + 256*R.
    const int base = 2 * seg0 * 8192 + row * 512 + tid;
#define LOADRAW(X, IDX)                                                      \
    {                                                                        \
        int _i = (IDX);                                                      \
        float2 v = t2p[_i];                                                  \
        if (sig == 0) { float2 p = p2p[_i]; v.x -= p.x; v.y -= p.y; }        \
        X = v;                                                               \
    }
    float2 r0, r1, r2, r3, r4, r5, r6, r7;
    LOADRAW(r0, base)
    LOADRAW(r1, base + 256)
    LOADRAW(r2, base + 8192)
    LOADRAW(r3, base + 8448)
    LOADRAW(r4, base + 16384)
    LOADRAW(r5, base + 16640)
    LOADRAW(r6, base + 24576)
    LOADRAW(r7, base + 24832)

    // ---- hoisted trig (segment-invariant) ----
    const float WA = 3.06796157577128245e-3f;      // 2*pi/2048
    const float CD = 0.99999882344642529f;         // cos(pi/2048)
    const float SD = 1.53398018628476550e-3f;      // sin(pi/2048)
    const float H  = 0.70710678118654752440f;      // sqrt(2)/2
    float sa, ca;
    __sincosf((float)tid * WA, &sa, &ca);          // window base; stage-A tw = (ca,-sa)
    // window weights per R (rotations of (ca,sa) by R*pi/4), w = (even, odd)
    float2 wv0, wv1, wv2, wv3, wv4, wv5, wv6, wv7;
#define MKW(W, CE, SE) { float cr = (CE), sr = (SE);                         \
        W = make_float2(1.0f - cr, 1.0f - (cr * CD - sr * SD)); }
    MKW(wv0, ca, sa)
    MKW(wv1, H * (ca - sa), H * (sa + ca))
    MKW(wv2, -sa, ca)
    MKW(wv3, -H * (ca + sa), H * (ca - sa))
    MKW(wv4, -ca, -sa)
    MKW(wv5, H * (sa - ca), -H * (sa + ca))
    MKW(wv6, sa, -ca)
    MKW(wv7, H * (ca + sa), H * (sa - ca))
#undef MKW
    // stage-B twiddle base (depends on tid&31 only)
    float sb, cb;
    __sincosf((float)(tid & 31) * -2.45436926061702596e-2f, &sb, &cb);  // -2*pi/256
    // stage-C twiddle base (depends on tid&3 only): constants
    float cc, ss;
    {
        const float TC1 = 0.98078528040323044913f, TS1 = -0.19509032201612826785f;
        const float TC2 = 0.92387953251128675613f, TS2 = -0.38268343236508977173f;
        const float TC3 = 0.83146961230254523708f, TS3 = -0.55557023301960222474f;
        int mq = tid & 3;
        cc = (mq & 2) ? ((mq & 1) ? TC3 : TC2) : ((mq & 1) ? TC1 : 1.0f);
        ss = (mq & 2) ? ((mq & 1) ? TS3 : TS2) : ((mq & 1) ? TS1 : 0.0f);
    }
    // untangle twiddles for bins k1 = K0+tid and k2 = k1+256 (-pi/8 rotation)
    float sn0, cs0, sn1, cs1;
    __sincosf(-1.53398078788564123e-3f * (float)(K0 + tid), &sn0, &cs0);  // -2*pi*k/4096
    {
        const float CU = 0.98078528040323044913f;   // cos(pi/8)
        const float SU = 0.19509032201612826785f;   // sin(pi/8)
        cs1 = cs0 * CU + sn0 * SU;
        sn1 = sn0 * CU - cs0 * SU;
    }

    float pw1 = 0.0f, pw2 = 0.0f;   // register power accumulators (2 bins/thread)
    float4* b4 = (float4*)buf;

    #pragma unroll 1
    for (int s = 0; s < ns; ++s) {
        // ---- window raw -> x
        float2 x0 = make_float2(r0.x * wv0.x, r0.y * wv0.y);
        float2 x1 = make_float2(r1.x * wv1.x, r1.y * wv1.y);
        float2 x2 = make_float2(r2.x * wv2.x, r2.y * wv2.y);
        float2 x3 = make_float2(r3.x * wv3.x, r3.y * wv3.y);
        float2 x4 = make_float2(r4.x * wv4.x, r4.y * wv4.y);
        float2 x5 = make_float2(r5.x * wv5.x, r5.y * wv5.y);
        float2 x6 = make_float2(r6.x * wv6.x, r6.y * wv6.y);
        float2 x7 = make_float2(r7.x * wv7.x, r7.y * wv7.y);

        // ---- shift overlap half + prefetch next segment's new half (issued
        // now, consumed next iteration -> latency hidden under this FFT)
        if (s + 1 < ns) {
            r0 = r4; r1 = r5; r2 = r6; r3 = r7;
            int nb = base + (s + 1) * 16384;
            LOADRAW(r4, nb + 16384)
            LOADRAW(r5, nb + 16640)
            LOADRAW(r6, nb + 24576)
            LOADRAW(r7, nb + 24832)
        }

        // ---- stage A: radix-8 stride 256, twiddle W2048^{tid*p} = (ca,-sa)^p
        dft8(x0, x1, x2, x3, x4, x5, x6, x7);
        twiddle8cs(x1, x2, x3, x4, x5, x6, x7, ca, -sa);
        buf[sw(tid)]        = x0;
        buf[sw(tid + 256)]  = x1;
        buf[sw(tid + 512)]  = x2;
        buf[sw(tid + 768)]  = x3;
        buf[sw(tid + 1024)] = x4;
        buf[sw(tid + 1280)] = x5;
        buf[sw(tid + 1536)] = x6;
        buf[sw(tid + 1792)] = x7;
        __syncthreads();

        // ---- stage B: radix-8 stride 32 within each 256-subFFT
        {
            const int baseB = (tid & 31) + 256 * (tid >> 5);
            x0 = buf[sw(baseB)];
            x1 = buf[sw(baseB + 32)];
            x2 = buf[sw(baseB + 64)];
            x3 = buf[sw(baseB + 96)];
            x4 = buf[sw(baseB + 128)];
            x5 = buf[sw(baseB + 160)];
            x6 = buf[sw(baseB + 192)];
            x7 = buf[sw(baseB + 224)];
            dft8(x0, x1, x2, x3, x4, x5, x6, x7);
            twiddle8cs(x1, x2, x3, x4, x5, x6, x7, cb, sb);
            buf[sw(baseB)]       = x0;
            buf[sw(baseB + 32)]  = x1;
            buf[sw(baseB + 64)]  = x2;
            buf[sw(baseB + 96)]  = x3;
            buf[sw(baseB + 128)] = x4;
            buf[sw(baseB + 160)] = x5;
            buf[sw(baseB + 192)] = x6;
            buf[sw(baseB + 224)] = x7;
        }
        __syncthreads();

        // ---- stage C: radix-8 stride 4 within each 32-subFFT
        {
            const int baseC = (tid & 3) + 32 * ((tid >> 2) & 7) + 256 * (tid >> 5);
            x0 = buf[sw(baseC)];
            x1 = buf[sw(baseC + 4)];
            x2 = buf[sw(baseC + 8)];
            x3 = buf[sw(baseC + 12)];
            x4 = buf[sw(baseC + 16)];
            x5 = buf[sw(baseC + 20)];
            x6 = buf[sw(baseC + 24)];
            x7 = buf[sw(baseC + 28)];
            dft8(x0, x1, x2, x3, x4, x5, x6, x7);
            twiddle8cs(x1, x2, x3, x4, x5, x6, x7, cc, ss);
            buf[sw(baseC)]      = x0;
            buf[sw(baseC + 4)]  = x1;
            buf[sw(baseC + 8)]  = x2;
            buf[sw(baseC + 12)] = x3;
            buf[sw(baseC + 16)] = x4;
            buf[sw(baseC + 20)] = x5;
            buf[sw(baseC + 24)] = x6;
            buf[sw(baseC + 28)] = x7;
        }
        __syncthreads();

        // ---- stage D fused with digit-reversal: quad n holds the 4 inputs of
        // the length-4 DFT for bins k = 512v + m, m = 64(n&7)+8((n>>3)&7)+(n>>6).
        // Only v=0 (bins 21..499) and v=3 (bins 1549..2027 = conj partners) are
        // needed: write X0 -> nat[ms(m)], X3 -> nat[512+ms(m)] (natural order).
#define QUAD(N)                                                              \
        {                                                                    \
            int n = (N);                                                     \
            int q4 = sw(4 * n) >> 1;                                         \
            float4 lo = b4[q4], hi = b4[q4 + 1];                             \
            float2 X0 = make_float2((lo.x + hi.x) + (lo.z + hi.z),           \
                                    (lo.y + hi.y) + (lo.w + hi.w));          \
            float D0x = lo.x - hi.x, D0y = lo.y - hi.y;                      \
            float D1x = lo.z - hi.z, D1y = lo.w - hi.w;                      \
            float2 X3 = make_float2(D0x - D1y, D0y + D1x);                   \
            int m = 64 * (n & 7) + 8 * ((n >> 3) & 7) + (n >> 6);            \
            int a = ms(m);                                                   \
            nat[a] = X0;                                                     \
            nat[512 + a] = X3;                                               \
        }
        QUAD(tid)
        QUAD(tid + 256)
#undef QUAD
        __syncthreads();

        // ---- untangle + power, accumulate in registers (linear, conflict-free)
        {
            int k = K0 + tid;                       // 21..276, always < 500
            float2 zk = nat[ms(k)];
            float2 zn = nat[512 + ms(512 - k)];     // Z[2048-k]
            float Ex = 0.5f * (zk.x + zn.x);
            float Ey = 0.5f * (zk.y - zn.y);
            float Ox = 0.5f * (zk.y + zn.y);
            float Oy = -0.5f * (zk.x - zn.x);
            float xr = Ex + Ox * cs0 - Oy * sn0;
            float xi = Ey + Ox * sn0 + Oy * cs0;
            pw1 += xr * xr + xi * xi;
        }
        if (tid < KEND - K0 - 256) {                // k2 = K0+256+tid < 500
            int k = K0 + 256 + tid;
            float2 zk = nat[ms(k)];
            float2 zn = nat[512 + ms(512 - k)];
            float Ex = 0.5f * (zk.x + zn.x);
            float Ey = 0.5f * (zk.y - zn.y);
            float Ox = 0.5f * (zk.y + zn.y);
            float Oy = -0.5f * (zk.x - zn.x);
            float xr = Ex + Ox * cs1 - Oy * sn1;
            float xi = Ey + Ox * sn1 + Oy * cs1;
            pw2 += xr * xr + xi * xi;
        }
        __syncthreads();   // nat reads done before next iteration's stage D
    }

    // ---- single atomic flush per thread (atomics cut 4x vs per-segment)
    {
        int i0 = (sig * NROWS + (row - ROW0)) * ACC_STRIDE;
        atomicAdd(&accR[i0 + tid], pw1);
        if (tid < KEND - K0 - 256) atomicAdd(&accR[i0 + 256 + tid], pw2);
    }
#undef LOADRAW
}

// Single block: out = sum over (row,k) of P_res/P_tgt, / 240.
// (dfreq=1, scale=480, mean(last 8)*16 => 2/480 = 1/240; /T cancels in ratio)
__global__ __launch_bounds__(256)
void reduce_kernel(const float* __restrict__ acc, float* __restrict__ out) {
    __shared__ float sh[256];
    int tid = threadIdx.x;
    float sum = 0.0f;
    for (int n = tid; n < NROWS * NFREQ; n += 256) {
        int r = n / NFREQ, k = n % NFREQ;
        float num = 0.0f, den = 0.0f;
        #pragma unroll
        for (int rep = 0; rep < NREP; ++rep) {
            num += acc[rep * ACC_ELEMS + r * ACC_STRIDE + k];
            den += acc[rep * ACC_ELEMS + (NROWS + r) * ACC_STRIDE + k];
        }
        sum += num / den;
    }
    sh[tid] = sum;
    __syncthreads();
    for (int s = 128; s > 0; s >>= 1) {
        if (tid < s) sh[tid] += sh[tid + s];
        __syncthreads();
    }
    if (tid == 0) out[0] = sh[0] * (1.0f / 240.0f);
}

extern "C" void kernel_launch(void* const* d_in, const int* in_sizes, int n_in,
                              void* d_out, int out_size, void* d_ws, size_t ws_size,
                              hipStream_t stream) {
    const float* pred = (const float*)d_in[0];
    const float* target = (const float*)d_in[1];
    float* acc = (float*)d_ws;   // NREP replicas of [2][NROWS][ACC_STRIDE] = 256 KiB

    hipMemsetAsync(acc, 0, NREP * ACC_ELEMS * sizeof(float), stream);
    psd_kernel<<<NBLOCKS, 256, 0, stream>>>(pred, target, acc);
    reduce_kernel<<<1, 256, 0, stream>>>(acc, (float*)d_out);
}